// Round 1
// baseline (491.865 us; speedup 1.0000x reference)
//
#include <hip/hip_runtime.h>

typedef __attribute__((ext_vector_type(8))) short short8;   // 8 bf16 = 4 VGPRs
typedef __attribute__((ext_vector_type(4))) float floatx4;  // MFMA accumulator

#define N_PTS 8192
#define D_DIM 256
#define N_PLANES 128

// round-to-nearest-even float -> bf16 bits
__device__ inline unsigned short f2bf(float f) {
    unsigned int x = __float_as_uint(f);
    unsigned int r = (x + 0x7fffu + ((x >> 16) & 1u)) >> 16;
    return (unsigned short)r;
}

// count of zero bytes in w (exact per-byte SWAR, no cross-byte carry)
__device__ inline int zbytes(unsigned int w) {
    unsigned int t = ((w & 0x7f7f7f7fu) + 0x7f7f7f7fu) | w | 0x7f7f7f7fu;
    return __popc(~t);  // ~t has only bit7 per byte set, iff byte == 0
}

// ---------------------------------------------------------------------------
// Kernel 1: row-normalize Z (fp32) -> Zn (bf16). One wave per row.
// ---------------------------------------------------------------------------
__global__ void norm_kernel(const float* __restrict__ Z,
                            unsigned short* __restrict__ Zn) {
    int n = blockIdx.x;
    int lane = threadIdx.x;  // 0..63
    const float4* zr = (const float4*)(Z + (size_t)n * D_DIM);
    float4 v = zr[lane];  // 64 lanes x 4 floats = 256
    float ss = v.x * v.x + v.y * v.y + v.z * v.z + v.w * v.w;
#pragma unroll
    for (int off = 32; off > 0; off >>= 1) ss += __shfl_down(ss, off);
    ss = __shfl(ss, 0);
    float inv = rsqrtf(ss);
    ushort4 o;
    o.x = f2bf(v.x * inv);
    o.y = f2bf(v.y * inv);
    o.z = f2bf(v.z * inv);
    o.w = f2bf(v.w * inv);
    ((ushort4*)(Zn + (size_t)n * D_DIM))[lane] = o;
}

// ---------------------------------------------------------------------------
// Kernel 2: LSH keys. Block = 128 threads (one per hyperplane), 8 points/block.
// keys4[n][w] : word w holds ballot bits of planes 32w..32w+31; byte b of the
// 16-byte key is the 8-bit signature of band b (bijective vs reference 2^r).
// ---------------------------------------------------------------------------
__global__ void keys_kernel(const float* __restrict__ Z,
                            const float* __restrict__ planes,
                            unsigned int* __restrict__ keys4) {
    __shared__ __align__(16) float zs[8][D_DIM];
    int t = threadIdx.x;  // 0..127 == plane index
    int base = blockIdx.x * 8;

    const float4* zsrc = (const float4*)(Z + (size_t)base * D_DIM);
    float4* zdst = (float4*)&zs[0][0];
#pragma unroll
    for (int i = 0; i < 4; ++i) zdst[t + i * 128] = zsrc[t + i * 128];
    __syncthreads();

    int wave = t >> 6, lane = t & 63;
    const float4* pr4 = (const float4*)(planes + (size_t)t * D_DIM);

    for (int g = 0; g < 8; ++g) {
        float dot = 0.f;
        const float4* zrow = (const float4*)&zs[g][0];
#pragma unroll
        for (int kk = 0; kk < D_DIM / 4; ++kk) {
            float4 p = pr4[kk];
            float4 z = zrow[kk];
            dot += p.x * z.x + p.y * z.y + p.z * z.z + p.w * z.w;
        }
        unsigned long long mask = __ballot(dot >= 0.0f);
        if (lane < 2) {
            keys4[(size_t)(base + g) * 4 + wave * 2 + lane] =
                (unsigned int)(mask >> (32 * lane));
        }
    }
}

// ---------------------------------------------------------------------------
// Kernel 3: sim GEMM (bf16 MFMA) + LSH-count epilogue.
// 128x128 tile per block, 4 waves in 2x2, each wave 64x64 via 4x4 MFMA tiles.
// K=256 fully unrolled (8 steps of 32). Fragments read direct from global
// (Zn is 4 MB -> L2 resident).
// ---------------------------------------------------------------------------
__global__ __launch_bounds__(256) void gemm_kernel(
    const unsigned short* __restrict__ Zn, const uint4* __restrict__ keys,
    float* __restrict__ out) {
    __shared__ uint4 krow[128];
    __shared__ uint4 kcol[128];
    int t = threadIdx.x;
    int rowBase = blockIdx.y * 128;
    int colBase = blockIdx.x * 128;
    if (t < 128)
        krow[t] = keys[rowBase + t];
    else
        kcol[t - 128] = keys[colBase + (t - 128)];

    int wave = t >> 6, lane = t & 63;
    int wm = wave >> 1, wn = wave & 1;
    int quad = lane >> 4, l16 = lane & 15;

    floatx4 acc[4][4] = {};

    int aRow = rowBase + wm * 64 + l16;
    int bRow = colBase + wn * 64 + l16;

#pragma unroll
    for (int kk = 0; kk < 8; ++kk) {
        int kOff = kk * 32 + quad * 8;
        short8 afr[4], bfr[4];
#pragma unroll
        for (int mt = 0; mt < 4; ++mt)
            afr[mt] = *(const short8*)(Zn + (size_t)(aRow + mt * 16) * D_DIM + kOff);
#pragma unroll
        for (int nt = 0; nt < 4; ++nt)
            bfr[nt] = *(const short8*)(Zn + (size_t)(bRow + nt * 16) * D_DIM + kOff);
#pragma unroll
        for (int mt = 0; mt < 4; ++mt)
#pragma unroll
            for (int nt = 0; nt < 4; ++nt)
                acc[mt][nt] = __builtin_amdgcn_mfma_f32_16x16x32_bf16(
                    afr[mt], bfr[nt], acc[mt][nt], 0, 0, 0);
    }

    __syncthreads();  // keys staged at kernel start

    // C/D layout: col = lane&15, row = quad*4 + reg  [m89/m91 verified]
#pragma unroll
    for (int mt = 0; mt < 4; ++mt) {
        int liBase = wm * 64 + mt * 16 + quad * 4;
#pragma unroll
        for (int nt = 0; nt < 4; ++nt) {
            int lj = wn * 64 + nt * 16 + l16;
            int gj = colBase + lj;
            uint4 kj = kcol[lj];
#pragma unroll
            for (int r = 0; r < 4; ++r) {
                int li = liBase + r;
                int gi = rowBase + li;
                float s = acc[mt][nt][r];
                float v = 0.0f;
                if (s >= 0.5f && gi != gj) {
                    uint4 ki = krow[li];
                    int c = zbytes(ki.x ^ kj.x) + zbytes(ki.y ^ kj.y) +
                            zbytes(ki.z ^ kj.z) + zbytes(ki.w ^ kj.w);
                    v = s * (float)c;
                }
                out[(size_t)gi * N_PTS + gj] = v;
            }
        }
    }
}

extern "C" void kernel_launch(void* const* d_in, const int* in_sizes, int n_in,
                              void* d_out, int out_size, void* d_ws,
                              size_t ws_size, hipStream_t stream) {
    const float* Z = (const float*)d_in[0];       // (8192, 256) fp32
    const float* planes = (const float*)d_in[1];  // (128, 256) fp32
    float* out = (float*)d_out;                   // (8192, 8192) fp32

    unsigned short* Zn = (unsigned short*)d_ws;  // 8192*256 bf16 = 4 MB
    unsigned int* keys4 =
        (unsigned int*)((char*)d_ws + (size_t)N_PTS * D_DIM * 2);  // 128 KB

    norm_kernel<<<N_PTS, 64, 0, stream>>>(Z, Zn);
    keys_kernel<<<N_PTS / 8, 128, 0, stream>>>(Z, planes, keys4);
    gemm_kernel<<<dim3(N_PTS / 128, N_PTS / 128), 256, 0, stream>>>(
        Zn, (const uint4*)keys4, out);
}

// Round 2
// 341.201 us; speedup vs baseline: 1.4416x; 1.4416x over previous
//
#include <hip/hip_runtime.h>

typedef __attribute__((ext_vector_type(8))) short short8;   // 8 bf16 = 4 VGPRs
typedef __attribute__((ext_vector_type(4))) float floatx4;  // MFMA accumulator

#define N_PTS 8192
#define D_DIM 256
#define N_PLANES 128

// round-to-nearest-even float -> bf16 bits
__device__ inline unsigned short f2bf(float f) {
    unsigned int x = __float_as_uint(f);
    unsigned int r = (x + 0x7fffu + ((x >> 16) & 1u)) >> 16;
    return (unsigned short)r;
}

// count of zero bytes in w (exact per-byte SWAR, no cross-byte carry)
__device__ inline int zbytes(unsigned int w) {
    unsigned int t = ((w & 0x7f7f7f7fu) + 0x7f7f7f7fu) | w | 0x7f7f7f7fu;
    return __popc(~t);  // ~t has only bit7 per byte set, iff byte == 0
}

// async global->LDS, 16B per lane; LDS dest must be base + lane*16 (m104/m108)
__device__ inline void load_lds16(const unsigned short* g, unsigned short* l) {
    __builtin_amdgcn_global_load_lds(
        (const __attribute__((address_space(1))) unsigned int*)g,
        (__attribute__((address_space(3))) unsigned int*)l, 16, 0, 0);
}

// ---------------------------------------------------------------------------
// Kernel 1: row-normalize Z (fp32) -> Zn (bf16). One wave per row.
// ---------------------------------------------------------------------------
__global__ void norm_kernel(const float* __restrict__ Z,
                            unsigned short* __restrict__ Zn) {
    int n = blockIdx.x;
    int lane = threadIdx.x;  // 0..63
    const float4* zr = (const float4*)(Z + (size_t)n * D_DIM);
    float4 v = zr[lane];  // 64 lanes x 4 floats = 256
    float ss = v.x * v.x + v.y * v.y + v.z * v.z + v.w * v.w;
#pragma unroll
    for (int off = 32; off > 0; off >>= 1) ss += __shfl_down(ss, off);
    ss = __shfl(ss, 0);
    float inv = rsqrtf(ss);
    ushort4 o;
    o.x = f2bf(v.x * inv);
    o.y = f2bf(v.y * inv);
    o.z = f2bf(v.z * inv);
    o.w = f2bf(v.w * inv);
    ((ushort4*)(Zn + (size_t)n * D_DIM))[lane] = o;
}

// ---------------------------------------------------------------------------
// Kernel 2: LSH keys. Block = 256 threads = 128 planes x 2 point-halves,
// 32 points per block. Points staged in LDS (broadcast reads); each thread
// reads its plane row ONCE (16B/step, register-cached across its 16 points).
// keys4[n][w]: word w = ballot bits of planes 32w..32w+31; byte b of the
// 16-byte key equals the reference band-b signature (same 2^r weighting).
// ---------------------------------------------------------------------------
__global__ __launch_bounds__(256) void keys_kernel(
    const float* __restrict__ Z, const float* __restrict__ planes,
    unsigned int* __restrict__ keys4) {
    __shared__ __align__(16) float zs[32][D_DIM];  // 32 KB
    int t = threadIdx.x;
    int base = blockIdx.x * 32;

    const float4* zsrc = (const float4*)(Z + (size_t)base * D_DIM);
    float4* zdst = (float4*)&zs[0][0];
#pragma unroll
    for (int i = 0; i < 8; ++i) zdst[t + i * 256] = zsrc[t + i * 256];
    __syncthreads();

    int p = t & 127;   // plane index
    int hf = t >> 7;   // 0/1 -> points 0..15 / 16..31
    int wave = t >> 6, lane = t & 63;
    const float4* pr = (const float4*)(planes + (size_t)p * D_DIM);

    float acc[16] = {};
    for (int kk = 0; kk < D_DIM / 4; ++kk) {
        float4 pv = pr[kk];
#pragma unroll
        for (int j = 0; j < 16; ++j) {
            float4 zv = *(const float4*)&zs[hf * 16 + j][kk * 4];
            acc[j] += pv.x * zv.x + pv.y * zv.y + pv.z * zv.z + pv.w * zv.w;
        }
    }

#pragma unroll
    for (int j = 0; j < 16; ++j) {
        unsigned long long mask = __ballot(acc[j] >= 0.0f);
        if (lane < 2) {
            keys4[(size_t)(base + hf * 16 + j) * 4 + (wave & 1) * 2 + lane] =
                (unsigned int)(mask >> (32 * lane));
        }
    }
}

// ---------------------------------------------------------------------------
// Kernel 3: sim GEMM (bf16 MFMA) + LSH-count epilogue.
// 128x128 tile / block, 4 waves (2x2), each wave 64x64 via 4x4 MFMA tiles.
// K staged in 4 chunks of BK=64 through LDS with global_load_lds (16B).
// LDS layout chunk-major: slot = c*128 + row (c = 16B-chunk within stage),
// so staging is lane-contiguous and ds_read_b128 is conflict-free (<=2-way).
// ---------------------------------------------------------------------------
__global__ __launch_bounds__(256) void gemm_kernel(
    const unsigned short* __restrict__ Zn, const uint4* __restrict__ keys,
    float* __restrict__ out) {
    __shared__ __align__(16) unsigned short As[1024 * 8];  // 16 KB: 8 chunks x 128 rows x 16B
    __shared__ __align__(16) unsigned short Bs[1024 * 8];  // 16 KB
    __shared__ uint4 krow[128];
    __shared__ uint4 kcol[128];

    int t = threadIdx.x;
    int rowBase = blockIdx.y * 128;
    int colBase = blockIdx.x * 128;
    if (t < 128)
        krow[t] = keys[rowBase + t];
    else
        kcol[t - 128] = keys[colBase + (t - 128)];

    int wave = t >> 6, lane = t & 63;
    int wm = wave >> 1, wn = wave & 1;
    int quad = lane >> 4, l16 = lane & 15;

    floatx4 acc[4][4] = {};

    for (int s = 0; s < 4; ++s) {
        __syncthreads();  // previous stage's LDS reads done (also fences keys)
#pragma unroll
        for (int i = 0; i < 4; ++i) {
            int sa = i * 256 + t;            // slot 0..1023
            int c = sa >> 7, row = sa & 127; // chunk, tile-row
            size_t gOff = (size_t)row * D_DIM + s * 64 + c * 8;
            load_lds16(Zn + (size_t)rowBase * D_DIM + gOff, &As[sa * 8]);
            load_lds16(Zn + (size_t)colBase * D_DIM + gOff, &Bs[sa * 8]);
        }
        __syncthreads();  // staging complete (vmcnt drained before barrier)

#pragma unroll
        for (int k2 = 0; k2 < 2; ++k2) {
            int cb = k2 * 4 + quad;
            short8 afr[4], bfr[4];
#pragma unroll
            for (int mt = 0; mt < 4; ++mt)
                afr[mt] = *(const short8*)&As[(cb * 128 + wm * 64 + mt * 16 + l16) * 8];
#pragma unroll
            for (int nt = 0; nt < 4; ++nt)
                bfr[nt] = *(const short8*)&Bs[(cb * 128 + wn * 64 + nt * 16 + l16) * 8];
#pragma unroll
            for (int mt = 0; mt < 4; ++mt)
#pragma unroll
                for (int nt = 0; nt < 4; ++nt)
                    acc[mt][nt] = __builtin_amdgcn_mfma_f32_16x16x32_bf16(
                        afr[mt], bfr[nt], acc[mt][nt], 0, 0, 0);
        }
    }

    // C/D layout: col = lane&15, row = quad*4 + reg  [m89/m91 verified]
#pragma unroll
    for (int mt = 0; mt < 4; ++mt) {
        int liBase = wm * 64 + mt * 16 + quad * 4;
#pragma unroll
        for (int nt = 0; nt < 4; ++nt) {
            int lj = wn * 64 + nt * 16 + l16;
            int gj = colBase + lj;
            uint4 kj = kcol[lj];
#pragma unroll
            for (int r = 0; r < 4; ++r) {
                int li = liBase + r;
                int gi = rowBase + li;
                float s = acc[mt][nt][r];
                float v = 0.0f;
                if (s >= 0.5f && gi != gj) {
                    uint4 ki = krow[li];
                    int c = zbytes(ki.x ^ kj.x) + zbytes(ki.y ^ kj.y) +
                            zbytes(ki.z ^ kj.z) + zbytes(ki.w ^ kj.w);
                    v = s * (float)c;
                }
                out[(size_t)gi * N_PTS + gj] = v;
            }
        }
    }
}

extern "C" void kernel_launch(void* const* d_in, const int* in_sizes, int n_in,
                              void* d_out, int out_size, void* d_ws,
                              size_t ws_size, hipStream_t stream) {
    const float* Z = (const float*)d_in[0];       // (8192, 256) fp32
    const float* planes = (const float*)d_in[1];  // (128, 256) fp32
    float* out = (float*)d_out;                   // (8192, 8192) fp32

    unsigned short* Zn = (unsigned short*)d_ws;  // 8192*256 bf16 = 4 MB
    unsigned int* keys4 =
        (unsigned int*)((char*)d_ws + (size_t)N_PTS * D_DIM * 2);  // 128 KB

    norm_kernel<<<N_PTS, 64, 0, stream>>>(Z, Zn);
    keys_kernel<<<N_PTS / 32, 256, 0, stream>>>(Z, planes, keys4);
    gemm_kernel<<<dim3(N_PTS / 128, N_PTS / 128), 256, 0, stream>>>(
        Zn, (const uint4*)keys4, out);
}